// Round 5
// baseline (793.467 us; speedup 1.0000x reference)
//
#include <hip/hip_runtime.h>
#include <hip/hip_cooperative_groups.h>

namespace cg = cooperative_groups;

#define N_NODES  200000
#define N_CHILD  32
#define N_LAYERS 8
#define BT       1024    // 16 waves/block
#define NB       256     // 1 block per CU -> all co-resident (16 waves/CU <= 32)

// All 8 layers fused into one cooperative kernel; grid.sync() between layers
// replaces 7 dependent-dispatch boundaries (launch + inter-kernel L2
// writeback/invalidate), which R1-R4's constant ~65us/layer across wildly
// different kernel bodies suggests is the real fixed cost.
__global__ __launch_bounds__(BT) void fused_kernel(
    const float* __restrict__ X,
    const float* __restrict__ wptr,
    const int*   __restrict__ child_idx,   // [N_LAYERS][N_NODES][N_CHILD]
    const int*   __restrict__ fun_ids,     // [N_LAYERS][N_NODES]
    float*       __restrict__ bufA,
    float*       __restrict__ bufB,
    float*       __restrict__ out)
{
    cg::grid_group grid = cg::this_grid();
    const int   node = blockIdx.x * BT + threadIdx.x;
    const float w0   = wptr[0];

    const float* cur = X;
    for (int l = 0; l < N_LAYERS; ++l) {
        float* nxt = (l == N_LAYERS - 1) ? out : ((l & 1) ? bufB : bufA);
        if (node < N_NODES) {
            const int4* ci = (const int4*)(child_idx
                               + ((size_t)l * N_NODES + node) * N_CHILD);
            float s0 = 0.0f, s1 = 0.0f;
            #pragma unroll
            for (int j = 0; j < N_CHILD / 4; ++j) {
                int4 c = ci[j];
                s0 += cur[c.x];
                s1 += cur[c.y];
                s0 += cur[c.z];
                s1 += cur[c.w];
            }
            float x = w0 * (s0 + s1);
            int fid = fun_ids[(size_t)l * N_NODES + node];
            float y;
            if (fid == 0)      y = tanhf(x);
            else if (fid == 1) y = 1.0f / (1.0f + __expf(-x));  // safe at +-inf
            else if (fid == 2) y = fmaxf(x, 0.0f);
            else               y = x;
            nxt[node] = y;
        }
        grid.sync();   // all threads, every layer (uniform control flow)
        cur = nxt;
    }
}

extern "C" void kernel_launch(void* const* d_in, const int* in_sizes, int n_in,
                              void* d_out, int out_size, void* d_ws, size_t ws_size,
                              hipStream_t stream) {
    const float* X         = (const float*)d_in[0];
    const float* w         = (const float*)d_in[1];
    const int*   child_idx = (const int*)d_in[2];
    const int*   fun_ids   = (const int*)d_in[3];
    float*       out       = (float*)d_out;
    float*       bufA      = (float*)d_ws;                    // 800 KB ping
    float*       bufB      = (float*)d_ws + 200704;           // pong (256B-aligned stride)

    void* args[] = { (void*)&X, (void*)&w, (void*)&child_idx, (void*)&fun_ids,
                     (void*)&bufA, (void*)&bufB, (void*)&out };
    hipLaunchCooperativeKernel((const void*)fused_kernel,
                               dim3(NB), dim3(BT), args, 0, stream);
}

// Round 6
// 499.586 us; speedup vs baseline: 1.5882x; 1.5882x over previous
//
#include <hip/hip_runtime.h>

#define N_NODES  200000
#define N_CHILD  32
#define N_LAYERS 8
#define CHUNK    40000   // floats per LDS chunk = 156.25 KB; 5 * 40000 = 200000 exactly
#define NCHUNK   5
#define NB       256     // 1 block per CU
#define NPB      782     // ceil(200000/256) nodes per block
#define BT       832     // 13 waves; 782/832 = 94% lanes active

// LDS sweep v3: stage the 800 KB value table through a 156 KB LDS window in
// 5 exact chunks. Probes are BRANCHLESS (cndmask on address + on value) so
// each probe is ~4 VALU + 1 pipelined ds_read -- no exec-mask branches,
// which is what sank R4. Global gather path (R1/R3/R5) is pinned at
// ~6 cyc/lane-address (L1 miss-slot limited, concurrency-insensitive);
// the LDS pipe serves the same probes at ~0.1-0.15 cyc/lane-address.
__global__ __launch_bounds__(BT) void layer_kernel(
    const float* __restrict__ vals_in,
    float*       __restrict__ vals_out,
    const int*   __restrict__ child_idx,   // [N_NODES][N_CHILD] this layer
    const int*   __restrict__ fun_ids,     // [N_NODES] this layer
    const float* __restrict__ wptr)
{
    __shared__ __align__(16) float lds[CHUNK];
    const int tid    = threadIdx.x;
    const int node   = blockIdx.x * NPB + tid;
    const bool active = (tid < NPB) && (node < N_NODES);

    // child indices -> registers (8x int4, coalesced)
    int idx[N_CHILD];
    int fid = 3;
    if (active) {
        const int4* ci = (const int4*)(child_idx + (size_t)node * N_CHILD);
        #pragma unroll
        for (int j = 0; j < N_CHILD / 4; ++j) {
            int4 c = ci[j];
            idx[4*j+0] = c.x; idx[4*j+1] = c.y;
            idx[4*j+2] = c.z; idx[4*j+3] = c.w;
        }
        fid = fun_ids[node];
    } else {
        #pragma unroll
        for (int j = 0; j < N_CHILD; ++j) idx[j] = 0;
    }

    float s = 0.0f;
    const float4* __restrict__ src4 = (const float4*)vals_in;  // chunk base 160000B: 16B-aligned
    #pragma unroll 1
    for (int c = 0; c < NCHUNK; ++c) {
        __syncthreads();   // previous pass done reading LDS
        {
            float4* dst4 = (float4*)lds;
            const int b4 = c * (CHUNK / 4);
            for (int i = tid; i < CHUNK / 4; i += BT) dst4[i] = src4[b4 + i];
        }
        __syncthreads();   // chunk staged
        const unsigned cbase = (unsigned)(c * CHUNK);
        #pragma unroll
        for (int j = 0; j < N_CHILD; ++j) {
            unsigned off = (unsigned)idx[j] - cbase;
            bool in  = off < (unsigned)CHUNK;
            float v  = lds[in ? off : 0u];   // always in-bounds, no branch
            s += in ? v : 0.0f;              // cndmask, no branch
        }
    }

    if (active) {
        float x = wptr[0] * s;
        float y;
        if (fid == 0)      y = tanhf(x);
        else if (fid == 1) y = 1.0f / (1.0f + __expf(-x));  // safe at +-inf
        else if (fid == 2) y = fmaxf(x, 0.0f);
        else               y = x;
        vals_out[node] = y;
    }
}

extern "C" void kernel_launch(void* const* d_in, const int* in_sizes, int n_in,
                              void* d_out, int out_size, void* d_ws, size_t ws_size,
                              hipStream_t stream) {
    const float* X         = (const float*)d_in[0];
    const float* w         = (const float*)d_in[1];
    const int*   child_idx = (const int*)d_in[2];
    const int*   fun_ids   = (const int*)d_in[3];
    float*       out       = (float*)d_out;
    float*       bufA      = (float*)d_ws;   // 800 KB ping buffer

    const float* cur = X;
    for (int l = 0; l < N_LAYERS; ++l) {
        // even layers -> bufA, odd layers -> d_out; layer 7 (last) -> d_out
        float* nxt = (l & 1) ? out : bufA;
        layer_kernel<<<NB, BT, 0, stream>>>(
            cur, nxt,
            child_idx + (size_t)l * N_NODES * N_CHILD,
            fun_ids   + (size_t)l * N_NODES,
            w);
        cur = nxt;
    }
}